// Round 1
// baseline (430.821 us; speedup 1.0000x reference)
//
#include <hip/hip_runtime.h>
#include <math.h>
#include <float.h>

#define LOUT 4
#define BATCH 4
#define NP 1000
#define NC 80
#define NM 64
#define ND 256
#define TT 784
#define NIMG (LOUT*BATCH)
#define CWTT (NC*TT)   // 62720

__device__ __forceinline__ float block_reduce_sum(float v, float* red) {
    int tid = threadIdx.x;
    red[tid] = v; __syncthreads();
    for (int s = blockDim.x >> 1; s > 0; s >>= 1) {
        if (tid < s) red[tid] += red[tid + s];
        __syncthreads();
    }
    float r = red[0]; __syncthreads();
    return r;
}

// ---------------- Kernel A: per-prior validity + in_both bitmask ----------------
__global__ void k_valid(const float* __restrict__ boxes, const float* __restrict__ gtb,
                        int* __restrict__ valid, unsigned long long* __restrict__ inboth,
                        int* __restrict__ hasvalid) {
    int img = blockIdx.y;
    int b = img % BATCH;
    int i = blockIdx.x * blockDim.x + threadIdx.x;
    __shared__ float g[NM * 4];
    for (int k = threadIdx.x; k < NM * 4; k += blockDim.x) g[k] = gtb[b * NM * 4 + k];
    __syncthreads();
    if (i >= NP) return;
    const float* bx = boxes + ((size_t)img * NP + i) * 4;
    float x0 = bx[0], y0 = bx[1], x1 = bx[2], y1 = bx[3];
    float cx = (x0 + x1) * 0.5f, cy = (y0 + y1) * 0.5f;
    float w = x1 - x0, h = y1 - y0;
    float rx = 2.5f * w, ry = 2.5f * h;
    bool any_gt = false, any_ct = false;
    unsigned long long ib = 0ull;
    for (int j = 0; j < NM; ++j) {
        float gx0 = g[j*4], gy0 = g[j*4+1], gx1 = g[j*4+2], gy1 = g[j*4+3];
        bool igt = (cx > gx0) && (cy > gy0) && (cx < gx1) && (cy < gy1);
        float gcx = (gx0 + gx1) * 0.5f, gcy = (gy0 + gy1) * 0.5f;
        bool ict = (cx > gcx - rx) && (cx < gcx + rx) && (cy > gcy - ry) && (cy < gcy + ry);
        any_gt |= igt; any_ct |= ict;
        if (igt && ict) ib |= (1ull << j);
    }
    bool v = any_gt || any_ct;
    valid[img * NP + i] = v ? 1 : 0;
    inboth[img * NP + i] = ib;
    if (v) atomicOr(&hasvalid[img], 1);
}

// ---------------- Kernel B: cost + iou matrices, column-major [img][j][i] ----------------
__global__ void k_cost(const float* __restrict__ logits, const float* __restrict__ boxes,
                       const float* __restrict__ gtb, const int* __restrict__ gcls_all,
                       const float* __restrict__ imsz,
                       const int* __restrict__ valid, const unsigned long long* __restrict__ inboth,
                       const int* __restrict__ hasvalid,
                       float* __restrict__ cost, float* __restrict__ iou_out) {
    int j = blockIdx.x, img = blockIdx.y, b = img % BATCH;
    float s = imsz[b], inv_s = 1.f / s;
    const float* gj = gtb + (b * NM + j) * 4;
    float gx0 = gj[0], gy0 = gj[1], gx1 = gj[2], gy1 = gj[3];
    int gc = gcls_all[b * NM + j];
    int hv = hasvalid[img];
    float garea = (gx1 - gx0) * (gy1 - gy0);
    float ngx0 = gx0 * inv_s, ngy0 = gy0 * inv_s, ngx1 = gx1 * inv_s, ngy1 = gy1 * inv_s;
    float ngarea = (ngx1 - ngx0) * (ngy1 - ngy0);
    size_t colbase = ((size_t)img * NM + j) * NP;
    for (int i = threadIdx.x; i < NP; i += blockDim.x) {
        const float* bx = boxes + ((size_t)img * NP + i) * 4;
        float x0 = bx[0], y0 = bx[1], x1 = bx[2], y1 = bx[3];
        // raw iou (mmdet, eps on union)
        float area = (x1 - x0) * (y1 - y0);
        float ltx = fmaxf(x0, gx0), lty = fmaxf(y0, gy0);
        float rbx = fminf(x1, gx1), rby = fminf(y1, gy1);
        float iw = fmaxf(rbx - ltx, 0.f), ih = fmaxf(rby - lty, 0.f);
        float inter = iw * ih;
        float uni = fmaxf(area + garea - inter, 1e-8f);
        float iou = inter / uni;
        // normalized giou cost
        float nx0 = x0 * inv_s, ny0 = y0 * inv_s, nx1 = x1 * inv_s, ny1 = y1 * inv_s;
        float narea = (nx1 - nx0) * (ny1 - ny0);
        float nltx = fmaxf(nx0, ngx0), nlty = fmaxf(ny0, ngy0);
        float nrbx = fminf(nx1, ngx1), nrby = fminf(ny1, ngy1);
        float niw = fmaxf(nrbx - nltx, 0.f), nih = fmaxf(nrby - nlty, 0.f);
        float ninter = niw * nih;
        float nuni = narea + ngarea - ninter;
        float niou = ninter / nuni;
        float ex0 = fminf(nx0, ngx0), ey0 = fminf(ny0, ngy0);
        float ex1 = fmaxf(nx1, ngx1), ey1 = fmaxf(ny1, ngy1);
        float earea = fmaxf(ex1 - ex0, 0.f) * fmaxf(ey1 - ey0, 0.f);
        float giou = niou - (earea - nuni) / earea;
        float giou_cost = 2.f * (1.f - giou);
        float l1 = 5.f * (fabsf(nx0 - ngx0) + fabsf(ny0 - ngy0) + fabsf(nx1 - ngx1) + fabsf(ny1 - ngy1));
        // FocalLossCost at class gc
        float x = logits[((size_t)img * NP + i) * NC + gc];
        float p = 1.f / (1.f + expf(-x));
        float neg = -logf(1.f - p + 1e-8f) * 0.75f * p * p;
        float pos = -logf(p + 1e-8f) * 0.25f * (1.f - p) * (1.f - p);
        float cls = 2.f * (pos - neg);
        bool vld = (valid[img * NP + i] != 0) || (hv == 0);
        bool inb = (((inboth[img * NP + i] >> j) & 1ull) != 0ull) || (hv == 0);
        float cst = cls + l1 + giou_cost + (inb ? 0.f : 100000.f);
        if (!vld) cst = 1e15f;
        cost[colbase + i] = cst;
        iou_out[colbase + i] = vld ? iou : 0.f;
    }
}

// ---------------- Kernel C: per-column top-10 iou sum -> dyn_k, then dyn_k-th smallest (cost,idx) ----------------
__global__ void k_topk(const float* __restrict__ cost, const float* __restrict__ iou,
                       float* __restrict__ kthc, int* __restrict__ kthi) {
    int col = blockIdx.x;
    const float* cc = cost + (size_t)col * NP;
    const float* ic = iou + (size_t)col * NP;
    __shared__ float sv[256]; __shared__ int si[256];
    __shared__ float spv; __shared__ int spi; __shared__ float ssum;
    int tid = threadIdx.x;
    if (tid == 0) { ssum = 0.f; }
    __syncthreads();
    // phase 1: top-10 largest iou (stable desc order, tie -> lower index first)
    float pv = FLT_MAX; int pi = -1;
    for (int it = 0; it < 10; ++it) {
        float bv = -FLT_MAX; int bi = NP;
        for (int i = tid; i < NP; i += 256) {
            float v = ic[i];
            bool allowed = (v < pv) || (v == pv && i > pi);
            if (allowed && ((v > bv) || (v == bv && i < bi))) { bv = v; bi = i; }
        }
        sv[tid] = bv; si[tid] = bi; __syncthreads();
        for (int s = 128; s > 0; s >>= 1) {
            if (tid < s) {
                if (sv[tid+s] > sv[tid] || (sv[tid+s] == sv[tid] && si[tid+s] < si[tid])) {
                    sv[tid] = sv[tid+s]; si[tid] = si[tid+s];
                }
            }
            __syncthreads();
        }
        if (tid == 0) { ssum += sv[0]; spv = sv[0]; spi = si[0]; }
        __syncthreads();
        pv = spv; pi = spi;
        __syncthreads();
    }
    float sum = ssum;
    int dk = (int)sum; if (dk < 1) dk = 1;   // astype(int32) truncation, max(.,1)
    // phase 2: dk-th smallest (cost, idx) lexicographic
    pv = -FLT_MAX; pi = -1;
    for (int it = 0; it < dk; ++it) {
        float bv = FLT_MAX; int bi = NP;
        for (int i = tid; i < NP; i += 256) {
            float v = cc[i];
            bool allowed = (v > pv) || (v == pv && i > pi);
            if (allowed && ((v < bv) || (v == bv && i < bi))) { bv = v; bi = i; }
        }
        sv[tid] = bv; si[tid] = bi; __syncthreads();
        for (int s = 128; s > 0; s >>= 1) {
            if (tid < s) {
                if (sv[tid+s] < sv[tid] || (sv[tid+s] == sv[tid] && si[tid+s] < si[tid])) {
                    sv[tid] = sv[tid+s]; si[tid] = si[tid+s];
                }
            }
            __syncthreads();
        }
        if (tid == 0) { spv = sv[0]; spi = si[0]; }
        __syncthreads();
        pv = spv; pi = spi;
        __syncthreads();
    }
    if (tid == 0) { kthc[col] = pv; kthi[col] = pi; }
}

// ---------------- Kernel D: matching resolution + l1/giou losses ----------------
__global__ void k_match(const float* __restrict__ cost,
                        const float* __restrict__ kthc, const int* __restrict__ kthi,
                        const float* __restrict__ boxes, const float* __restrict__ gtb,
                        const float* __restrict__ imsz,
                        int* __restrict__ fg, int* __restrict__ gt_ind,
                        float* __restrict__ accum) {
    int img = blockIdx.y, b = img % BATCH;
    int i = blockIdx.x * blockDim.x + threadIdx.x;
    __shared__ float skc[NM]; __shared__ int ski[NM];
    __shared__ float red[256];
    if (threadIdx.x < NM) {
        skc[threadIdx.x] = kthc[img * NM + threadIdx.x];
        ski[threadIdx.x] = kthi[img * NM + threadIdx.x];
    }
    __syncthreads();
    float l1 = 0.f, gl = 0.f, f = 0.f;
    if (i < NP) {
        int cnt = 0, first = -1;
        float bc = FLT_MAX; int bj = 0;
        for (int j = 0; j < NM; ++j) {
            float c = cost[((size_t)img * NM + j) * NP + i];
            bool m = (c < skc[j]) || (c == skc[j] && i <= ski[j]);
            if (m) { cnt++; if (first < 0) first = j; }
            if (c < bc) { bc = c; bj = j; }
        }
        int gi = 0, isfg = 0;
        if (cnt > 1) { gi = bj; isfg = 1; }
        else if (cnt == 1) { gi = first; isfg = 1; }
        fg[img * NP + i] = isfg;
        gt_ind[img * NP + i] = gi;
        if (isfg) {
            float inv = 1.f / imsz[b];
            const float* bx = boxes + ((size_t)img * NP + i) * 4;
            const float* gj = gtb + (b * NM + gi) * 4;
            float nx0 = bx[0]*inv, ny0 = bx[1]*inv, nx1 = bx[2]*inv, ny1 = bx[3]*inv;
            float gx0 = gj[0]*inv, gy0 = gj[1]*inv, gx1 = gj[2]*inv, gy1 = gj[3]*inv;
            l1 = fabsf(nx0-gx0) + fabsf(ny0-gy0) + fabsf(nx1-gx1) + fabsf(ny1-gy1);
            float a1 = (nx1-nx0)*(ny1-ny0), a2 = (gx1-gx0)*(gy1-gy0);
            float ltx = fmaxf(nx0,gx0), lty = fmaxf(ny0,gy0);
            float rbx = fminf(nx1,gx1), rby = fminf(ny1,gy1);
            float iw = fmaxf(rbx-ltx,0.f), ih = fmaxf(rby-lty,0.f);
            float inter = iw*ih, uni = a1+a2-inter, iou = inter/uni;
            float ex0 = fminf(nx0,gx0), ey0 = fminf(ny0,gy0);
            float ex1 = fmaxf(nx1,gx1), ey1 = fmaxf(ny1,gy1);
            float ea = fmaxf(ex1-ex0,0.f)*fmaxf(ey1-ey0,0.f);
            float giou = iou - (ea-uni)/ea;
            gl = 1.f - giou;
            f = 1.f;
        }
    }
    float sl1 = block_reduce_sum(l1, red);
    float sgl = block_reduce_sum(gl, red);
    float sf  = block_reduce_sum(f, red);
    if (threadIdx.x == 0) {
        atomicAdd(&accum[img*5+1], sl1);
        atomicAdd(&accum[img*5+2], sgl);
        atomicAdd(&accum[img*5+4], sf);
    }
}

// ---------------- Kernel E: sigmoid focal classification loss over all N*C ----------------
__global__ void k_focal(const float* __restrict__ logits, const int* __restrict__ fg,
                        const int* __restrict__ gt_ind, const int* __restrict__ gcls_all,
                        float* __restrict__ accum) {
    int img = blockIdx.y, b = img % BATCH;
    int idx = blockIdx.x * blockDim.x + threadIdx.x;
    __shared__ float red[256];
    float v = 0.f;
    if (idx < NP * NC) {
        int i = idx / NC, c = idx % NC;
        float x = logits[(size_t)img * NP * NC + idx];
        int lab = 0;
        if (fg[img * NP + i]) {
            int gc = gcls_all[b * NM + gt_ind[img * NP + i]];
            lab = (c == gc) ? 1 : 0;
        }
        float p = 1.f / (1.f + expf(-x));
        float ax = fabsf(x);
        float sp = log1pf(expf(-ax));            // = -log_sigmoid(|x|)
        float ls_pos = fminf(x, 0.f) - sp;       // log_sigmoid(x)
        float ls_neg = fminf(-x, 0.f) - sp;      // log_sigmoid(-x)
        if (lab) v = 0.25f * (-ls_pos) * (1.f - p) * (1.f - p);
        else     v = 0.75f * (-ls_neg) * p * p;
    }
    float sv = block_reduce_sum(v, red);
    if (threadIdx.x == 0) atomicAdd(&accum[img*5+0], sv);
}

// ---------------- Kernel F: dice mask loss, grouped by (img, gt) ----------------
__global__ void __launch_bounds__(256) k_mask(
        const float* __restrict__ pfeat, const float* __restrict__ wmask,
        const float* __restrict__ gtm, const int* __restrict__ gcls_all,
        const int* __restrict__ fg, const int* __restrict__ gt_ind,
        float* __restrict__ accum) {
    int col = blockIdx.x;
    int img = col / NM, j = col % NM, b = img % BATCH;
    __shared__ float gm[TT];
    __shared__ int list[NP];
    __shared__ int s_cnt;
    __shared__ float red[256];
    __shared__ float pf[8 * ND];
    int tid = threadIdx.x;
    if (tid == 0) s_cnt = 0;
    for (int t = tid; t < TT; t += 256) gm[t] = gtm[((size_t)(b * NM + j)) * TT + t];
    __syncthreads();
    float lg = 0.f;
    for (int t = tid; t < TT; t += 256) lg += gm[t];
    float gmsum = block_reduce_sum(lg, red);
    for (int i = tid; i < NP; i += 256)
        if (fg[img * NP + i] && gt_ind[img * NP + i] == j) {
            int p = atomicAdd(&s_cnt, 1);
            list[p] = i;
        }
    __syncthreads();
    int cnt = s_cnt;
    if (cnt == 0) return;
    int c = gcls_all[b * NM + j];
    float mk_acc = 0.f;
    for (int base = 0; base < cnt; base += 8) {
        int P = min(8, cnt - base);
        for (int idx = tid; idx < 8 * ND; idx += 256) {
            int p = idx >> 8, d = idx & 255;
            pf[idx] = (p < P) ? pfeat[((size_t)img * NP + list[base + p]) * ND + d] : 0.f;
        }
        __syncthreads();
        float acc[4][8];
        #pragma unroll
        for (int k = 0; k < 4; ++k)
            #pragma unroll
            for (int p = 0; p < 8; ++p) acc[k][p] = 0.f;
        for (int d = 0; d < ND; ++d) {
            const float* wr = wmask + (size_t)d * CWTT + (size_t)c * TT;
            float pv[8];
            #pragma unroll
            for (int p = 0; p < 8; ++p) pv[p] = pf[p * ND + d];
            #pragma unroll
            for (int k = 0; k < 4; ++k) {
                int t = tid + k * 256;
                if (t < TT) {
                    float w = wr[t];
                    #pragma unroll
                    for (int p = 0; p < 8; ++p) acc[k][p] += pv[p] * w;
                }
            }
        }
        for (int p = 0; p < P; ++p) {
            float li = 0.f, lm = 0.f;
            #pragma unroll
            for (int k = 0; k < 4; ++k) {
                int t = tid + k * 256;
                if (t < TT) {
                    float m = 1.f / (1.f + expf(-acc[k][p]));
                    li += m * gm[t];
                    lm += m;
                }
            }
            float I = block_reduce_sum(li, red);
            float Ms = block_reduce_sum(lm, red);
            if (tid == 0) mk_acc += 1.f - 2.f * I / (Ms + gmsum + 1e-8f);
        }
        __syncthreads();
    }
    if (tid == 0) atomicAdd(&accum[img*5+3], mk_acc);
}

// ---------------- Final: per-l normalize and weight ----------------
__global__ void k_final(const float* __restrict__ accum, float* __restrict__ out) {
    if (threadIdx.x == 0 && blockIdx.x == 0) {
        float tot[4] = {0.f, 0.f, 0.f, 0.f};
        for (int l = 0; l < LOUT; ++l) {
            float s[5] = {0.f, 0.f, 0.f, 0.f, 0.f};
            for (int b = 0; b < BATCH; ++b)
                for (int k = 0; k < 5; ++k) s[k] += accum[(l * BATCH + b) * 5 + k];
            for (int k = 0; k < 4; ++k) tot[k] += s[k] / s[4];
        }
        const float w[4] = {2.f, 5.f, 2.f, 5.f};
        for (int k = 0; k < 4; ++k) out[k] = w[k] * tot[k] / (float)LOUT;
    }
}

extern "C" void kernel_launch(void* const* d_in, const int* in_sizes, int n_in,
                              void* d_out, int out_size, void* d_ws, size_t ws_size,
                              hipStream_t stream) {
    const float* logits = (const float*)d_in[0];
    const float* boxes  = (const float*)d_in[1];
    const float* pfeat  = (const float*)d_in[2];
    const float* gtb    = (const float*)d_in[3];
    const float* gtm    = (const float*)d_in[4];
    const float* imsz   = (const float*)d_in[5];
    const float* wmask  = (const float*)d_in[6];
    const int*   gcls   = (const int*)d_in[7];

    char* ws = (char*)d_ws;
    size_t off = 0;
    auto alloc = [&](size_t bytes) -> void* {
        void* p = ws + off;
        off = (off + bytes + 255) & ~(size_t)255;
        return p;
    };
    float* cost = (float*)alloc((size_t)NIMG * NM * NP * sizeof(float));
    float* iou  = (float*)alloc((size_t)NIMG * NM * NP * sizeof(float));
    int* valid  = (int*)alloc((size_t)NIMG * NP * sizeof(int));
    unsigned long long* inboth = (unsigned long long*)alloc((size_t)NIMG * NP * sizeof(unsigned long long));
    int* hasvalid = (int*)alloc(NIMG * sizeof(int));
    float* kthc = (float*)alloc(NIMG * NM * sizeof(float));
    int* kthi   = (int*)alloc(NIMG * NM * sizeof(int));
    int* fg     = (int*)alloc((size_t)NIMG * NP * sizeof(int));
    int* gti    = (int*)alloc((size_t)NIMG * NP * sizeof(int));
    float* accum = (float*)alloc(NIMG * 5 * sizeof(float));

    hipMemsetAsync(hasvalid, 0, NIMG * sizeof(int), stream);
    hipMemsetAsync(accum, 0, NIMG * 5 * sizeof(float), stream);

    k_valid<<<dim3((NP + 255) / 256, NIMG), 256, 0, stream>>>(boxes, gtb, valid, inboth, hasvalid);
    k_cost<<<dim3(NM, NIMG), 256, 0, stream>>>(logits, boxes, gtb, gcls, imsz, valid, inboth, hasvalid, cost, iou);
    k_topk<<<NIMG * NM, 256, 0, stream>>>(cost, iou, kthc, kthi);
    k_match<<<dim3((NP + 255) / 256, NIMG), 256, 0, stream>>>(cost, kthc, kthi, boxes, gtb, imsz, fg, gti, accum);
    k_focal<<<dim3((NP * NC + 255) / 256, NIMG), 256, 0, stream>>>(logits, fg, gti, gcls, accum);
    k_mask<<<NIMG * NM, 256, 0, stream>>>(pfeat, wmask, gtm, gcls, fg, gti, accum);
    k_final<<<1, 64, 0, stream>>>(accum, (float*)d_out);
}